// Round 2
// baseline (313.255 us; speedup 1.0000x reference)
//
#include <hip/hip_runtime.h>
#include <hip/hip_bf16.h>
#include <math.h>

typedef __bf16 bf16x8 __attribute__((ext_vector_type(8)));
typedef float floatx4 __attribute__((ext_vector_type(4)));

#define ATT_SCALE 0.35355339059327373f  // DH^-0.5, DH=8

__device__ __forceinline__ __bf16 f2b(float x) { return (__bf16)x; }

// ---------------------------------------------------------------------------
// K1: Q = p@wq, Ks = (p@wk)*SCALE, V = p@wv  (rows 0..2047), q1 = queries@cq_wq
// grid 2304 x 64
// ---------------------------------------------------------------------------
__global__ void k_proj(const float* __restrict__ p, const float* __restrict__ quer,
                       const float* __restrict__ wq, const float* __restrict__ wk,
                       const float* __restrict__ wv, const float* __restrict__ cq_wq,
                       float* __restrict__ Q, float* __restrict__ Ks,
                       float* __restrict__ V, float* __restrict__ q1) {
  int blk = blockIdx.x, t = threadIdx.x;
  __shared__ float xr[64];
  if (blk < 2048) {
    xr[t] = p[blk * 64 + t];
    __syncthreads();
    float aq = 0.f, ak = 0.f, av = 0.f;
    for (int c = 0; c < 64; c++) {
      float x = xr[c];
      aq += x * wq[c * 64 + t];
      ak += x * wk[c * 64 + t];
      av += x * wv[c * 64 + t];
    }
    Q[blk * 64 + t] = aq;
    Ks[blk * 64 + t] = ak * ATT_SCALE;
    V[blk * 64 + t] = av;
  } else {
    int r = blk - 2048;  // 0..255 query rows
    xr[t] = quer[r * 64 + t];
    __syncthreads();
    float a = 0.f;
    for (int c = 0; c < 64; c++) a += xr[c] * cq_wq[c * 64 + t];
    q1[r * 64 + t] = a;
  }
}

// ---------------------------------------------------------------------------
// K2: edge attention, fully fused per (b,i) block.
//  E[j,hk] = e[b,i,j,:]@we  via MFMA 16x16x32 bf16 (fp32->bf16 in-register)
//  score[j,h] = sum_k E*Q_i*Ks_j ; w = exp(score)*kRW*mask ; out = (w@V)/sum
//  epilogue: p_attn@wo_p + tanh + p + h = h_c ;  h_c@cq_wkv -> Kc,Vc
// grid 2048 x 256 (4 waves; wave w owns j in [w*64, w*64+64))
// ---------------------------------------------------------------------------
__global__ __launch_bounds__(256) void k_edge(
    const float* __restrict__ e, const float* __restrict__ we,
    const float* __restrict__ krw, const float* __restrict__ mask,
    const float* __restrict__ hin, const float* __restrict__ pin,
    const float* __restrict__ wo, const float* __restrict__ cq_wkv,
    const float* __restrict__ Q, const float* __restrict__ Ks,
    const float* __restrict__ V, float* __restrict__ Kc, float* __restrict__ Vc) {
  int bi = blockIdx.x;          // b*256 + i
  int b = bi >> 8;
  int t = threadIdx.x;
  int w = t >> 6, l = t & 63;
  int l15 = l & 15, quad = l >> 4, half8 = (l >> 3) & 1, d = l & 7;

  // B-fragments of we: B[k=quad*8+jj][n=l15], per n-tile (nt) and K-chunk (kc)
  bf16x8 wfrag[4][2];
  for (int nt = 0; nt < 4; nt++)
    for (int kc = 0; kc < 2; kc++)
      for (int jj = 0; jj < 8; jj++)
        wfrag[nt][kc][jj] = f2b(we[(kc * 32 + quad * 8 + jj) * 64 + nt * 16 + l15]);

  float qv[4];
  for (int nt = 0; nt < 4; nt++) qv[nt] = Q[bi * 64 + nt * 16 + l15];
  float mi = mask[bi];

  float aout[4] = {0.f, 0.f, 0.f, 0.f};
  float aden[4] = {0.f, 0.f, 0.f, 0.f};

  for (int mt = 0; mt < 4; mt++) {
    int j0 = w * 64 + mt * 16;
    // A-fragments from global e (fp32), converted: A[m=l15][k=quad*8+jj]
    const float* ep = e + ((long)bi * 256 + j0 + l15) * 64 + quad * 8;
    float4 ea = *reinterpret_cast<const float4*>(ep);
    float4 eb4 = *reinterpret_cast<const float4*>(ep + 4);
    float4 ec = *reinterpret_cast<const float4*>(ep + 32);
    float4 ed4 = *reinterpret_cast<const float4*>(ep + 36);
    bf16x8 a0, a1;
    a0[0] = f2b(ea.x); a0[1] = f2b(ea.y); a0[2] = f2b(ea.z); a0[3] = f2b(ea.w);
    a0[4] = f2b(eb4.x); a0[5] = f2b(eb4.y); a0[6] = f2b(eb4.z); a0[7] = f2b(eb4.w);
    a1[0] = f2b(ec.x); a1[1] = f2b(ec.y); a1[2] = f2b(ec.z); a1[3] = f2b(ec.w);
    a1[4] = f2b(ed4.x); a1[5] = f2b(ed4.y); a1[6] = f2b(ed4.z); a1[7] = f2b(ed4.w);

    int jr0 = j0 + quad * 4;  // D rows this lane owns: jr0..jr0+3
    float krw_r[4], mj_r[4];
    for (int r = 0; r < 4; r++) {
      krw_r[r] = krw[(long)bi * 256 + jr0 + r];
      mj_r[r] = mask[b * 256 + jr0 + r];
    }
    for (int nt = 0; nt < 4; nt++) {
      floatx4 acc = {0.f, 0.f, 0.f, 0.f};
      acc = __builtin_amdgcn_mfma_f32_16x16x32_bf16(a0, wfrag[nt][0], acc, 0, 0, 0);
      acc = __builtin_amdgcn_mfma_f32_16x16x32_bf16(a1, wfrag[nt][1], acc, 0, 0, 0);
      int hk = nt * 16 + l15;      // D col = lane&15
      int hbase = hk & 56;         // head*8
      for (int r = 0; r < 4; r++) {
        int jr = jr0 + r;          // D row = quad*4 + r
        float s = acc[r] * qv[nt] * Ks[(b * 256 + jr) * 64 + hk];
        // head-sum over the 8 k's (lanes differing in low 3 bits)
        s += __shfl_xor(s, 1);
        s += __shfl_xor(s, 2);
        s += __shfl_xor(s, 4);
        float wg = __expf(s) * krw_r[r] * mj_r[r];
        aden[nt] += wg;
        aout[nt] += wg * V[(b * 256 + jr) * 64 + hbase + d];
      }
    }
  }
  // reduce across row-groups (quad): j-coverage union
  for (int nt = 0; nt < 4; nt++) {
    float o = aout[nt], dn = aden[nt];
    o += __shfl_xor(o, 16); o += __shfl_xor(o, 32);
    dn += __shfl_xor(dn, 16); dn += __shfl_xor(dn, 32);
    aout[nt] = o; aden[nt] = dn;
  }

  __shared__ float red[4][64];
  __shared__ float redden[4][8];
  __shared__ float pav[64];
  __shared__ float hcl[64];
  if (l < 16) {
    for (int nt = 0; nt < 4; nt++) {
      int head = nt * 2 + half8;
      red[w][head * 8 + d] = aout[nt];
      if (d == 0) redden[w][head] = aden[nt];
    }
  }
  __syncthreads();
  if (t < 64) {
    int head = t >> 3;
    float num = red[0][t] + red[1][t] + red[2][t] + red[3][t];
    float den = redden[0][head] + redden[1][head] + redden[2][head] + redden[3][head];
    num *= mi;
    den = fmaxf(den * mi, 1e-6f);
    pav[t] = num / den;  // p_attn[b,i,head*8+d]
  }
  __syncthreads();
  if (t < 64) {
    float a = 0.f;
    for (int c = 0; c < 64; c++) a += pav[c] * wo[c * 64 + t];
    hcl[t] = hin[bi * 64 + t] + pin[bi * 64 + t] + tanhf(a);
  }
  __syncthreads();
  if (t < 128) {
    float a = 0.f;
    for (int c = 0; c < 64; c++) a += hcl[c] * cq_wkv[c * 128 + t];
    if (t < 64) Kc[bi * 64 + t] = a;
    else        Vc[bi * 64 + t - 64] = a;
  }
}

// ---------------------------------------------------------------------------
// T2: perceiver cross-attn per (b,h). clamp(-5,5); masked -> -5 (matches ref).
// grid 64 x 256 ; thread t: row r=t>>3, j-slice g=t&7
// ---------------------------------------------------------------------------
__global__ void k_cross(const float* __restrict__ q1, const float* __restrict__ Kc,
                        const float* __restrict__ Vc, const float* __restrict__ mask,
                        float* __restrict__ oc) {
  int bh = blockIdx.x, b = bh >> 3, h = bh & 7;
  int t = threadIdx.x, r = t >> 3, g = t & 7;
  __shared__ float qL[32][8];
  qL[r][g] = q1[(b * 32 + r) * 64 + h * 8 + g];
  __syncthreads();
  float num[8] = {0.f, 0.f, 0.f, 0.f, 0.f, 0.f, 0.f, 0.f};
  float den = 0.f;
  for (int jj = 0; jj < 32; jj++) {
    int j = jj * 8 + g;
    const float* kp = Kc + (b * 256 + j) * 64 + h * 8;
    float s = 0.f;
    for (int dd = 0; dd < 8; dd++) s += qL[r][dd] * kp[dd];
    s *= ATT_SCALE;
    float mj = mask[b * 256 + j];
    s = (mj > 0.5f) ? s : -1e30f;
    s = fminf(fmaxf(s, -5.f), 5.f);
    float ex = __expf(s);
    den += ex;
    const float* vp = Vc + (b * 256 + j) * 64 + h * 8;
    for (int dd = 0; dd < 8; dd++) num[dd] += ex * vp[dd];
  }
  den += __shfl_xor(den, 1); den += __shfl_xor(den, 2); den += __shfl_xor(den, 4);
  for (int dd = 0; dd < 8; dd++) {
    float v = num[dd];
    v += __shfl_xor(v, 1); v += __shfl_xor(v, 2); v += __shfl_xor(v, 4);
    num[dd] = v;
  }
  oc[(b * 32 + r) * 64 + h * 8 + g] = num[g] / den;
}

// ---------------------------------------------------------------------------
// TA: q_out = resid + attn_in@Wo + bo ; qq = q_out@wql ; kv = q_out@wkvl
// grid 256 x 64
// ---------------------------------------------------------------------------
__global__ void k_projqkv(const float* __restrict__ attn_in, const float* __restrict__ Wo,
                          const float* __restrict__ bo, const float* __restrict__ residp,
                          const float* __restrict__ wql, const float* __restrict__ wkvl,
                          float* __restrict__ q_out, float* __restrict__ qq,
                          float* __restrict__ kvb) {
  int r = blockIdx.x, t = threadIdx.x;
  __shared__ float oL[64];
  __shared__ float qL[64];
  oL[t] = attn_in[r * 64 + t];
  __syncthreads();
  float a = 0.f;
  for (int c = 0; c < 64; c++) a += oL[c] * Wo[c * 64 + t];
  float qvv = residp[r * 64 + t] + a + bo[t];
  q_out[r * 64 + t] = qvv;
  qL[t] = qvv;
  __syncthreads();
  float aq = 0.f, ak = 0.f, av = 0.f;
  for (int c = 0; c < 64; c++) {
    float x = qL[c];
    aq += x * wql[c * 64 + t];
    ak += x * wkvl[c * 128 + t];
    av += x * wkvl[c * 128 + 64 + t];
  }
  qq[r * 64 + t] = aq;
  kvb[r * 128 + t] = ak;
  kvb[r * 128 + 64 + t] = av;
}

// ---------------------------------------------------------------------------
// T4: latent self-attn per (b,h), 32 keys, clamp(-5,5), no mask
// grid 64 x 256
// ---------------------------------------------------------------------------
__global__ void k_sattn(const float* __restrict__ qq, const float* __restrict__ kvb,
                        float* __restrict__ os) {
  int bh = blockIdx.x, b = bh >> 3, h = bh & 7;
  int t = threadIdx.x, r = t >> 3, g = t & 7;
  __shared__ float qL[32][8];
  qL[r][g] = qq[(b * 32 + r) * 64 + h * 8 + g];
  __syncthreads();
  float num[8] = {0.f, 0.f, 0.f, 0.f, 0.f, 0.f, 0.f, 0.f};
  float den = 0.f;
  for (int jj = 0; jj < 4; jj++) {
    int j = jj * 8 + g;
    const float* kp = kvb + (b * 32 + j) * 128 + h * 8;
    float s = 0.f;
    for (int dd = 0; dd < 8; dd++) s += qL[r][dd] * kp[dd];
    s *= ATT_SCALE;
    s = fminf(fmaxf(s, -5.f), 5.f);
    float ex = __expf(s);
    den += ex;
    for (int dd = 0; dd < 8; dd++) num[dd] += ex * kp[64 + dd];
  }
  den += __shfl_xor(den, 1); den += __shfl_xor(den, 2); den += __shfl_xor(den, 4);
  for (int dd = 0; dd < 8; dd++) {
    float v = num[dd];
    v += __shfl_xor(v, 1); v += __shfl_xor(v, 2); v += __shfl_xor(v, 4);
    num[dd] = v;
  }
  os[(b * 32 + r) * 64 + h * 8 + g] = num[g] / den;
}

// ---------------------------------------------------------------------------
// TB: final: q2 = qprev + os@Wo + bo ; x=q2@oq_w ; LN1 ; ffn ; LN2 -> out
// grid 256 x 64 (one wave per row => shfl LayerNorm)
// ---------------------------------------------------------------------------
__global__ void k_final(const float* __restrict__ os, const float* __restrict__ Wo,
                        const float* __restrict__ bo, const float* __restrict__ qprev,
                        const float* __restrict__ oqw, const float* __restrict__ g1,
                        const float* __restrict__ b1, const float* __restrict__ w1,
                        const float* __restrict__ w2, const float* __restrict__ g2,
                        const float* __restrict__ b2v, float* __restrict__ out) {
  int r = blockIdx.x, t = threadIdx.x;
  __shared__ float oL[64];
  __shared__ float q2L[64];
  __shared__ float yL[64];
  __shared__ float hhs[128];
  oL[t] = os[r * 64 + t];
  __syncthreads();
  float a = 0.f;
  for (int c = 0; c < 64; c++) a += oL[c] * Wo[c * 64 + t];
  float q2 = qprev[r * 64 + t] + a + bo[t];
  q2L[t] = q2;
  __syncthreads();
  float x = 0.f;
  for (int c = 0; c < 64; c++) x += q2L[c] * oqw[c * 64 + t];
  // LN1
  float m = x;
  for (int off = 1; off < 64; off <<= 1) m += __shfl_xor(m, off);
  m *= (1.f / 64.f);
  float dv = x - m, vv = dv * dv;
  for (int off = 1; off < 64; off <<= 1) vv += __shfl_xor(vv, off);
  vv *= (1.f / 64.f);
  float y = dv * rsqrtf(vv + 1e-5f) * g1[t] + b1[t];
  yL[t] = y;
  __syncthreads();
  float h1 = 0.f, h2 = 0.f;
  for (int c = 0; c < 64; c++) {
    float xx = yL[c];
    h1 += xx * w1[c * 128 + t];
    h2 += xx * w1[c * 128 + 64 + t];
  }
  hhs[t] = fmaxf(h1, 0.f);
  hhs[t + 64] = fmaxf(h2, 0.f);
  __syncthreads();
  float ff = 0.f;
  for (int c = 0; c < 128; c++) ff += hhs[c] * w2[c * 64 + t];
  float z = y + ff;
  // LN2
  float m2 = z;
  for (int off = 1; off < 64; off <<= 1) m2 += __shfl_xor(m2, off);
  m2 *= (1.f / 64.f);
  float dz = z - m2, v2 = dz * dz;
  for (int off = 1; off < 64; off <<= 1) v2 += __shfl_xor(v2, off);
  v2 *= (1.f / 64.f);
  float z2 = dz * rsqrtf(v2 + 1e-5f) * g2[t] + b2v[t];
  out[r * 64 + t] = z2;
}

// ---------------------------------------------------------------------------
extern "C" void kernel_launch(void* const* d_in, const int* in_sizes, int n_in,
                              void* d_out, int out_size, void* d_ws, size_t ws_size,
                              hipStream_t stream) {
  const float* h_in   = (const float*)d_in[0];
  const float* p_in   = (const float*)d_in[1];
  const float* e_in   = (const float*)d_in[2];
  const float* krw    = (const float*)d_in[3];
  const float* quer   = (const float*)d_in[4];
  const float* mask   = (const float*)d_in[5];
  const float* wq_p   = (const float*)d_in[6];
  const float* wk_p   = (const float*)d_in[7];
  const float* we_p   = (const float*)d_in[8];
  const float* wv_p   = (const float*)d_in[9];
  const float* wo_p   = (const float*)d_in[10];
  const float* cq_wq  = (const float*)d_in[11];
  const float* cq_wkv = (const float*)d_in[12];
  const float* cq_wo  = (const float*)d_in[13];
  const float* cq_bo  = (const float*)d_in[14];
  const float* sa_wq  = (const float*)d_in[15];
  const float* sa_wkv = (const float*)d_in[16];
  const float* sa_wo  = (const float*)d_in[17];
  const float* sa_bo  = (const float*)d_in[18];
  const float* oq_w   = (const float*)d_in[19];
  const float* ln1_g  = (const float*)d_in[20];
  const float* ln1_b  = (const float*)d_in[21];
  const float* ffn_w1 = (const float*)d_in[22];
  const float* ffn_w2 = (const float*)d_in[23];
  const float* ln2_g  = (const float*)d_in[24];
  const float* ln2_b  = (const float*)d_in[25];

  float* ws = (float*)d_ws;
  float* Q   = ws;              // 131072
  float* Ks  = Q + 131072;      // 131072
  float* V   = Ks + 131072;     // 131072
  float* q1  = V + 131072;      // 16384
  float* Kc  = q1 + 16384;      // 131072
  float* Vc  = Kc + 131072;     // 131072
  float* oc  = Vc + 131072;     // 16384
  float* q0  = oc + 16384;      // 16384
  float* qq  = q0 + 16384;      // 16384
  float* kvb = qq + 16384;      // 32768
  float* osa = kvb + 32768;     // 16384
  float* qc1 = osa + 16384;     // 16384   total ~3.1 MB

  k_proj<<<2304, 64, 0, stream>>>(p_in, quer, wq_p, wk_p, wv_p, cq_wq, Q, Ks, V, q1);
  k_edge<<<2048, 256, 0, stream>>>(e_in, we_p, krw, mask, h_in, p_in, wo_p, cq_wkv,
                                   Q, Ks, V, Kc, Vc);
  k_cross<<<64, 256, 0, stream>>>(q1, Kc, Vc, mask, oc);
  k_projqkv<<<256, 64, 0, stream>>>(oc, cq_wo, cq_bo, quer,
                                    sa_wq, sa_wkv, q0, qq, kvb);
  k_sattn<<<64, 256, 0, stream>>>(qq, kvb, osa);
  k_projqkv<<<256, 64, 0, stream>>>(osa, sa_wo, sa_bo, q0,
                                    sa_wq + 4096, sa_wkv + 8192, qc1, qq, kvb);
  k_sattn<<<64, 256, 0, stream>>>(qq, kvb, osa);
  k_final<<<256, 64, 0, stream>>>(osa, sa_wo + 4096, sa_bo + 64, qc1, oq_w,
                                  ln1_g, ln1_b, ffn_w1, ffn_w2, ln2_g, ln2_b,
                                  (float*)d_out);
}